// Round 2
// baseline (302.115 us; speedup 1.0000x reference)
//
#include <hip/hip_runtime.h>
#include <hip/hip_bf16.h>

#define NN 4
#define LL 8192
#define HH 8
#define DD 64
#define NH 32                 // n*h combos
#define ROW_STRIDE (HH*DD)    // 512 floats between consecutive s rows
#define TILE 16
#define LDS_PAD 68            // row stride in LDS floats (272 B -> balanced b128 writes)
#define KV_ELEMS 4160         // 65*64 (64x64 KV + ksum row)

__device__ __forceinline__ float phi(float x) {
  // elu(x*temp) + 1 ; temp = 64^(-0.25) = 0.353553390593...
  float t = x * 0.35355339059327373f;
  return t > 0.f ? t + 1.f : __expf(t);
}

// ---------------- Kernel A: partial KV (and ksum) over s-chunks ----------------
// lane = d. Each lane accumulates KV[m][d_lane] for m=0..63 in 64 VGPRs.
// __launch_bounds__(256,4): min 4 waves/EU -> <=128 VGPR -> acc[64]+kreg[16]
// stay in registers (R1 showed 52 VGPR = spilled-to-scratch, 200 us).
__global__ __launch_bounds__(256, 4) void kv_partial_kernel(
    const float* __restrict__ K, const float* __restrict__ V,
    float* __restrict__ part, int nchunk)
{
  const int nh    = blockIdx.x / nchunk;
  const int chunk = blockIdx.x % nchunk;
  const int n = nh >> 3, h = nh & 7;
  const int tid = threadIdx.x;
  const int w = tid >> 6, lane = tid & 63;
  const int rows_per_block = LL / nchunk;
  const int rows_per_wave  = rows_per_block >> 2;
  const int s_begin = chunk * rows_per_block + w * rows_per_wave;

  const float* kbase = K + ((size_t)n * LL * HH + h) * DD;
  const float* vbase = V + ((size_t)n * LL * HH + h) * DD;

  __shared__ float v_lds[4][TILE * LDS_PAD];

  float acc[64];
#pragma unroll
  for (int m = 0; m < 64; ++m) acc[m] = 0.f;
  float ksum = 0.f;

  const int lr = lane >> 2, seg = lane & 3;   // 4 lanes per staged row

  for (int t0 = 0; t0 < rows_per_wave; t0 += TILE) {
    const int s0 = s_begin + t0;

    // ---- stage V tile (raw copy), 16 rows x 64 floats, per-wave region ----
    const float* vrow = vbase + (size_t)(s0 + lr) * ROW_STRIDE;
    float* vl = &v_lds[w][lr * LDS_PAD];
#pragma unroll
    for (int i = 0; i < 4; ++i) {
      const int c = i * 16 + seg * 4;          // lanes 0..3 cover 64B contiguous
      float4 vv = *(const float4*)(vrow + c);
      *(float4*)(vl + c) = vv;
    }

    // ---- K column for this lane (d = lane), 16 rows, coalesced dwords ----
    float kreg[TILE];
    const float* kcol = kbase + lane;
#pragma unroll
    for (int j = 0; j < TILE; ++j)
      kreg[j] = kcol[(size_t)(s0 + j) * ROW_STRIDE];
#pragma unroll
    for (int j = 0; j < TILE; ++j)
      kreg[j] = phi(kreg[j]);

    // ---- accumulate outer products ----
#pragma unroll
    for (int j = 0; j < TILE; ++j) {
      const float kf = kreg[j];
      ksum += kf;
      const float* vr = &v_lds[w][j * LDS_PAD];
#pragma unroll
      for (int m = 0; m < 64; m += 4) {
        float4 vv = *(const float4*)(vr + m);   // broadcast b128 (uniform addr)
        acc[m+0] += vv.x * kf;
        acc[m+1] += vv.y * kf;
        acc[m+2] += vv.z * kf;
        acc[m+3] += vv.w * kf;
      }
    }
  }

  // ---- write this wave's partial: p = blockIdx.x*4 + w (nh-major) ----
  float* o = part + ((size_t)blockIdx.x * 4 + w) * KV_ELEMS;
#pragma unroll
  for (int m = 0; m < 64; ++m) o[m * 64 + lane] = acc[m];   // [m][d] coalesced
  o[4096 + lane] = ksum;
}

// ---------------- Kernel B: reduce partials -> final KV + ksum per nh ----------------
__global__ __launch_bounds__(256) void kv_reduce_kernel(
    const float* __restrict__ part, float* __restrict__ kvf, int np)
{
  const int nh = blockIdx.x / 17;
  const int ec = blockIdx.x % 17;
  const int e = ec * 256 + threadIdx.x;
  if (e >= KV_ELEMS) return;
  const float* p = part + (size_t)nh * np * KV_ELEMS + e;
  float s = 0.f;
  for (int i = 0; i < np; ++i) s += p[(size_t)i * KV_ELEMS];
  kvf[(size_t)nh * KV_ELEMS + e] = s;
}

// ---------------- Kernel C: out[l][m] = z_l * (phi(q)_l . KV[m][:]) ----------------
// lane = m. KV row in 64 VGPRs (launch_bounds(256,4) -> <=128 VGPR, no spill).
__global__ __launch_bounds__(256, 4) void attn_out_kernel(
    const float* __restrict__ Q, const float* __restrict__ kvf,
    float* __restrict__ out, int nlchunk)
{
  const int nh    = blockIdx.x / nlchunk;
  const int chunk = blockIdx.x % nlchunk;
  const int n = nh >> 3, h = nh & 7;
  const int tid = threadIdx.x;
  const int w = tid >> 6, lane = tid & 63;
  const int rows_per_block = LL / nlchunk;
  const int rows_per_wave  = rows_per_block >> 2;
  const int row_begin = chunk * rows_per_block + w * rows_per_wave;

  const float* qbase = Q + ((size_t)n * LL * HH + h) * DD;
  const float* kvb   = kvf + (size_t)nh * KV_ELEMS;

  // KV[lane][d] into registers (L2-resident, small)
  float kv[64];
#pragma unroll
  for (int d = 0; d < 64; d += 4) {
    float4 t = *(const float4*)(kvb + lane * 64 + d);
    kv[d] = t.x; kv[d+1] = t.y; kv[d+2] = t.z; kv[d+3] = t.w;
  }
  const float ks = kvb[4096 + lane];

  __shared__ float q_lds[4][TILE * LDS_PAD];
  const int lr = lane >> 2, seg = lane & 3;

  for (int t0 = 0; t0 < rows_per_wave; t0 += TILE) {
    const int r0 = row_begin + t0;

    // ---- stage phi(Q) tile ----
    const float* qrow = qbase + (size_t)(r0 + lr) * ROW_STRIDE;
    float* ql = &q_lds[w][lr * LDS_PAD];
#pragma unroll
    for (int i = 0; i < 4; ++i) {
      const int c = i * 16 + seg * 4;
      float4 qv = *(const float4*)(qrow + c);
      qv.x = phi(qv.x); qv.y = phi(qv.y); qv.z = phi(qv.z); qv.w = phi(qv.w);
      *(float4*)(ql + c) = qv;
    }

    // ---- per row: z + matvec ----
#pragma unroll
    for (int j = 0; j < TILE; ++j) {
      const float* qr = &q_lds[w][j * LDS_PAD];

      // z denominator: per-lane product + butterfly (scheduler hides under matvec)
      float p = qr[lane] * ks;
#pragma unroll
      for (int off = 32; off; off >>= 1) p += __shfl_xor(p, off, 64);
      const float z = 1.0f / (p + 1e-6f);

      float a = 0.f;
#pragma unroll
      for (int d = 0; d < 64; d += 4) {
        float4 q4 = *(const float4*)(qr + d);   // broadcast b128
        a += q4.x * kv[d]   + q4.y * kv[d+1]
           + q4.z * kv[d+2] + q4.w * kv[d+3];
      }

      const int row = r0 + j;
      out[((size_t)nh * LL + row) * DD + lane] = a * z;  // coalesced
    }
  }
}

extern "C" void kernel_launch(void* const* d_in, const int* in_sizes, int n_in,
                              void* d_out, int out_size, void* d_ws, size_t ws_size,
                              hipStream_t stream)
{
  const float* Q = (const float*)d_in[0];
  const float* K = (const float*)d_in[1];
  const float* V = (const float*)d_in[2];
  float* out = (float*)d_out;
  float* ws  = (float*)d_ws;

  // pick largest nchunk whose partial buffer fits the workspace
  int nchunk = 16;
  while (nchunk > 1) {
    size_t need = ((size_t)NH * nchunk * 4 + NH) * KV_ELEMS * sizeof(float);
    if (need <= ws_size) break;
    nchunk >>= 1;
  }
  float* part = ws;
  float* kvf  = ws + (size_t)NH * nchunk * 4 * KV_ELEMS;

  hipLaunchKernelGGL(kv_partial_kernel, dim3(NH * nchunk), dim3(256), 0, stream,
                     K, V, part, nchunk);
  hipLaunchKernelGGL(kv_reduce_kernel, dim3(NH * 17), dim3(256), 0, stream,
                     part, kvf, nchunk * 4);
  hipLaunchKernelGGL(attn_out_kernel, dim3(NH * 64), dim3(256), 0, stream,
                     Q, kvf, out, 64);
}

// Round 3
// 264.431 us; speedup vs baseline: 1.1425x; 1.1425x over previous
//
#include <hip/hip_runtime.h>
#include <hip/hip_bf16.h>

#define NN 4
#define LL 8192
#define HH 8
#define DD 64
#define NH 32                 // n*h combos
#define RS  (HH*DD)           // 512 floats between consecutive s rows
#define AT  32                // A-kernel tile rows
#define QPAD 68               // q/k/v LDS row stride (272B = 17*16 -> float4-aligned)
#define KV_ELEMS 4160         // 64x64 kvT + 64 ksum
#define CCH 32                // C-kernel chunks per nh

__device__ __forceinline__ float phi(float x) {
  // elu(x*temp) + 1 ; temp = 64^(-0.25)
  float t = x * 0.35355339059327373f;
  return t > 0.f ? t + 1.f : __expf(t);
}

// ---------------- Kernel A: partial KV^T (and ksum) over s-chunks ----------------
// 2D register blocking: thread (dg,mg) owns acc[4d][4m] (16 floats -> no spill).
// k/v tiles staged in block LDS; all LDS reads broadcast or 2-way (free).
__global__ __launch_bounds__(256) void kv_partial_kernel(
    const float* __restrict__ K, const float* __restrict__ V,
    float* __restrict__ part, int nchunk)
{
  const int nh    = blockIdx.x / nchunk;
  const int chunk = blockIdx.x % nchunk;
  const int n = nh >> 3, h = nh & 7;
  const int tid = threadIdx.x;
  const int dg = tid >> 4, mg = tid & 15;
  const int d0 = dg * 4,  m0 = mg * 4;
  const int rows_pb = LL / nchunk;
  const int s_begin = chunk * rows_pb;

  const float* kbase = K + ((size_t)n * LL * HH + h) * DD;
  const float* vbase = V + ((size_t)n * LL * HH + h) * DD;

  __shared__ float kT[AT][QPAD];
  __shared__ float vT[AT][QPAD];

  float acc[4][4];
#pragma unroll
  for (int i = 0; i < 4; ++i)
#pragma unroll
    for (int j = 0; j < 4; ++j) acc[i][j] = 0.f;
  float ks[4] = {0.f, 0.f, 0.f, 0.f};

  for (int t0 = 0; t0 < rows_pb; t0 += AT) {
    // ---- stage: 32 rows x 64 floats each of K (phi'd) and V (raw) ----
    // thread loads rows (dg) and (dg+16), cols m0..m0+3 (coalesced 256B/row)
#pragma unroll
    for (int rep = 0; rep < 2; ++rep) {
      const int lr = dg + rep * 16;
      const size_t g = (size_t)(s_begin + t0 + lr) * RS + m0;
      float4 k4 = *(const float4*)(kbase + g);
      float4 v4 = *(const float4*)(vbase + g);
      k4.x = phi(k4.x); k4.y = phi(k4.y); k4.z = phi(k4.z); k4.w = phi(k4.w);
      *(float4*)(&kT[lr][m0]) = k4;
      *(float4*)(&vT[lr][m0]) = v4;
    }
    __syncthreads();

    // ---- accumulate: per row, k4 (broadcast) x v4 (2-way) outer product ----
#pragma unroll 8
    for (int j = 0; j < AT; ++j) {
      float4 k4 = *(const float4*)(&kT[j][d0]);   // 4 uniq addrs/wave: broadcast
      float4 v4 = *(const float4*)(&vT[j][m0]);   // 16 uniq, 2-way: free
      ks[0] += k4.x; ks[1] += k4.y; ks[2] += k4.z; ks[3] += k4.w;
      const float kk[4] = {k4.x, k4.y, k4.z, k4.w};
      const float vv[4] = {v4.x, v4.y, v4.z, v4.w};
#pragma unroll
      for (int i = 0; i < 4; ++i)
#pragma unroll
        for (int jj = 0; jj < 4; ++jj) acc[i][jj] += kk[i] * vv[jj];
    }
    __syncthreads();
  }

  // ---- write per-block partial, kvT layout [d][m] + ksum row ----
  float* po = part + (size_t)blockIdx.x * KV_ELEMS;
#pragma unroll
  for (int i = 0; i < 4; ++i) {
    float4 o = {acc[i][0], acc[i][1], acc[i][2], acc[i][3]};
    *(float4*)(po + (d0 + i) * 64 + m0) = o;      // coalesced
  }
  if (mg == 0) {
    float4 o = {ks[0], ks[1], ks[2], ks[3]};
    *(float4*)(po + 4096 + d0) = o;
  }
}

// ---------------- Kernel B: reduce partials -> kvf[nh][4160] ----------------
__global__ __launch_bounds__(256) void kv_reduce_kernel(
    const float* __restrict__ part, float* __restrict__ kvf, int np)
{
  const int nh = blockIdx.x / 17;
  const int ec = blockIdx.x % 17;
  const int e = ec * 256 + threadIdx.x;
  if (e >= KV_ELEMS) return;
  const float* p = part + (size_t)nh * np * KV_ELEMS + e;
  float s = 0.f;
  for (int i = 0; i < np; ++i) s += p[(size_t)i * KV_ELEMS];
  kvf[(size_t)nh * KV_ELEMS + e] = s;
}

// ---------------- Kernel C: out[l][m] = z_l * sum_d phi(q)[l][d] kvT[d][m] ----------------
// thread owns 4 rows x 4 m (acc[16]); kvT + ksum in LDS (block-wide),
// phi(q) staged per 64-row macro tile.
__global__ __launch_bounds__(256) void attn_out_kernel(
    const float* __restrict__ Q, const float* __restrict__ kvf,
    float* __restrict__ out)
{
  const int nh    = blockIdx.x / CCH;
  const int chunk = blockIdx.x % CCH;
  const int n = nh >> 3, h = nh & 7;
  const int tid = threadIdx.x;
  const int rg = tid >> 4, mg = tid & 15;
  const int m0 = mg * 4;
  const int rows_pb = LL / CCH;            // 256
  const int row_begin = chunk * rows_pb;

  const float* qbase = Q + ((size_t)n * LL * HH + h) * DD;
  const float* kvb   = kvf + (size_t)nh * KV_ELEMS;

  __shared__ float kvT[64 * 64];           // stride 64: m-reads are 2-way (free)
  __shared__ float ksL[64];
  __shared__ float qT[64][QPAD];

  // stage kvT (16 float4/thread, coalesced) + ksum
#pragma unroll
  for (int i = 0; i < 4; ++i) {
    const int off = i * 1024 + tid * 4;
    *(float4*)(kvT + off) = *(const float4*)(kvb + off);
  }
  if (tid < 16) *(float4*)(ksL + tid * 4) = *(const float4*)(kvb + 4096 + tid * 4);
  __syncthreads();

  for (int t0 = 0; t0 < rows_pb; t0 += 64) {
    // ---- stage phi(Q): 64 rows x 64 cols; thread does 4 rows (rg, +16,+32,+48) ----
#pragma unroll
    for (int rep = 0; rep < 4; ++rep) {
      const int lr = rg + rep * 16;
      float4 q4 = *(const float4*)(qbase + (size_t)(row_begin + t0 + lr) * RS + m0);
      q4.x = phi(q4.x); q4.y = phi(q4.y); q4.z = phi(q4.z); q4.w = phi(q4.w);
      *(float4*)(&qT[lr][m0]) = q4;
    }
    __syncthreads();

    float acc[4][4];
#pragma unroll
    for (int i = 0; i < 4; ++i)
#pragma unroll
      for (int j = 0; j < 4; ++j) acc[i][j] = 0.f;
    float zacc[4] = {0.f, 0.f, 0.f, 0.f};

#pragma unroll 4
    for (int dc = 0; dc < 16; ++dc) {
      const int d0 = dc * 4;
      float q4[4][4];
#pragma unroll
      for (int i = 0; i < 4; ++i)
        *(float4*)q4[i] = *(const float4*)(&qT[rg * 4 + i][d0]);  // broadcast
      float4 ks4 = *(const float4*)(ksL + d0);                     // uniform
      const float ksa[4] = {ks4.x, ks4.y, ks4.z, ks4.w};
#pragma unroll
      for (int kk = 0; kk < 4; ++kk) {
        float4 kv4 = *(const float4*)(kvT + (d0 + kk) * 64 + m0);  // 2-way: free
        const float kva[4] = {kv4.x, kv4.y, kv4.z, kv4.w};
#pragma unroll
        for (int i = 0; i < 4; ++i) {
#pragma unroll
          for (int j = 0; j < 4; ++j) acc[i][j] += q4[i][kk] * kva[j];
          zacc[i] += q4[i][kk] * ksa[kk];
        }
      }
    }
    __syncthreads();   // qT reused next macro-tile

    // ---- epilogue: scale by z, store 4 rows x float4 (coalesced segments) ----
#pragma unroll
    for (int i = 0; i < 4; ++i) {
      const float z = 1.0f / (zacc[i] + 1e-6f);
      const int row = row_begin + t0 + rg * 4 + i;
      float4 o = {acc[i][0] * z, acc[i][1] * z, acc[i][2] * z, acc[i][3] * z};
      *(float4*)(out + ((size_t)nh * LL + row) * DD + m0) = o;
    }
  }
}

extern "C" void kernel_launch(void* const* d_in, const int* in_sizes, int n_in,
                              void* d_out, int out_size, void* d_ws, size_t ws_size,
                              hipStream_t stream)
{
  const float* Q = (const float*)d_in[0];
  const float* K = (const float*)d_in[1];
  const float* V = (const float*)d_in[2];
  float* out = (float*)d_out;
  float* ws  = (float*)d_ws;

  // adaptive split-k: largest nchunk whose (partials + kvf) fits ws
  int nchunk = 32;
  while (nchunk > 1) {
    size_t need = ((size_t)NH * nchunk + NH) * KV_ELEMS * sizeof(float);
    if (need <= ws_size) break;
    nchunk >>= 1;
  }
  float* part = ws;
  float* kvf  = ws + (size_t)NH * nchunk * KV_ELEMS;

  hipLaunchKernelGGL(kv_partial_kernel, dim3(NH * nchunk), dim3(256), 0, stream,
                     K, V, part, nchunk);
  hipLaunchKernelGGL(kv_reduce_kernel, dim3(NH * 17), dim3(256), 0, stream,
                     part, kvf, nchunk);
  hipLaunchKernelGGL(attn_out_kernel, dim3(NH * CCH), dim3(256), 0, stream,
                     Q, kvf, out);
}

// Round 4
// 253.850 us; speedup vs baseline: 1.1901x; 1.0417x over previous
//
#include <hip/hip_runtime.h>
#include <hip/hip_bf16.h>

#define NN 4
#define LL 8192
#define HH 8
#define DD 64
#define NH 32                 // n*h combos
#define RS  (HH*DD)           // 512 floats between consecutive s rows
#define KV_ELEMS 4160         // 64x64 partial kvT [d][m] + ksum[d]
#define CCH 32                // C-kernel chunks per nh

typedef __attribute__((ext_vector_type(8))) short bf16x8;   // 8 bf16 (4 VGPR)
typedef __attribute__((ext_vector_type(4))) float f32x4;    // acc

__device__ __forceinline__ float phi(float x) {
  // elu(x*temp) + 1 ; temp = 64^(-0.25)
  float t = x * 0.35355339059327373f;
  return t > 0.f ? t + 1.f : __expf(t);
}
__device__ __forceinline__ short f2bf(float x) {
  __hip_bfloat16 h = __float2bfloat16(x);                  // RN
  return (short)__builtin_bit_cast(unsigned short, h);
}
__device__ __forceinline__ float bf2f(short s) {
  __hip_bfloat16 h = __builtin_bit_cast(__hip_bfloat16, (unsigned short)s);
  return __bfloat162float(h);
}
// split fp32 -> hi + lo bf16 (combined ~16-bit mantissa)
__device__ __forceinline__ void split2(float x, short& hi, short& lo) {
  hi = f2bf(x);
  lo = f2bf(x - bf2f(hi));
}

// ---------------- Kernel A: partial kvT[d][m] += phi(K)^T V over s-chunk ----------------
// MFMA 16x16x32, split-bf16 (3 mfma per tile-kstep). NO LDS: fragment lanes
// load their k-contiguous 8-element runs straight from global (coalesced 64B
// segments; 2-wave duplication absorbed by L1).
// wave w: d_super=(w>>1)*32 (A side), m_super=(w&1)*32 (B side); 2x2 16-tiles.
__global__ __launch_bounds__(256) void kv_partial_kernel(
    const float* __restrict__ K, const float* __restrict__ V,
    float* __restrict__ part, int sch)
{
  const int nh    = blockIdx.x / sch;
  const int chunk = blockIdx.x % sch;
  const int n = nh >> 3, h = nh & 7;
  const int tid = threadIdx.x;
  const int w = tid >> 6, lane = tid & 63;
  const int q = lane >> 4, p = lane & 15;
  const int d_super = (w >> 1) * 32, m_super = (w & 1) * 32;
  const int rows_pb = LL / sch;
  const int s_base  = chunk * rows_pb;

  const float* kbase = K + ((size_t)n * LL * HH + h) * DD;
  const float* vbase = V + ((size_t)n * LL * HH + h) * DD;

  f32x4 acc[2][2] = {};
  float ksacc[2] = {0.f, 0.f};

  for (int step = 0; step < rows_pb / 32; ++step) {
    const int s0 = s_base + step * 32 + q * 8;   // this lane's 8-s run

    // ---- A frags: phi(K), d = d_super + dt*16 + p, s = s0..s0+7 ----
    bf16x8 ahi[2], alo[2];
#pragma unroll
    for (int dt = 0; dt < 2; ++dt) {
      const float* kp = kbase + (size_t)s0 * RS + d_super + dt * 16 + p;
      float f[8];
#pragma unroll
      for (int j = 0; j < 8; ++j) f[j] = phi(kp[(size_t)j * RS]);
#pragma unroll
      for (int j = 0; j < 8; ++j) ksacc[dt] += f[j];
#pragma unroll
      for (int j = 0; j < 8; ++j) { short hi, lo; split2(f[j], hi, lo); ahi[dt][j] = hi; alo[dt][j] = lo; }
    }

    // ---- B frags: V raw, m = m_super + mt*16 + p, s = s0..s0+7 ----
    bf16x8 bhi[2], blo[2];
#pragma unroll
    for (int mt = 0; mt < 2; ++mt) {
      const float* vp = vbase + (size_t)s0 * RS + m_super + mt * 16 + p;
      float f[8];
#pragma unroll
      for (int j = 0; j < 8; ++j) f[j] = vp[(size_t)j * RS];
#pragma unroll
      for (int j = 0; j < 8; ++j) { short hi, lo; split2(f[j], hi, lo); bhi[mt][j] = hi; blo[mt][j] = lo; }
    }

    // ---- 4 tiles x 3 split-mfma ----
#pragma unroll
    for (int dt = 0; dt < 2; ++dt)
#pragma unroll
      for (int mt = 0; mt < 2; ++mt) {
        acc[dt][mt] = __builtin_amdgcn_mfma_f32_16x16x32_bf16(ahi[dt], bhi[mt], acc[dt][mt], 0, 0, 0);
        acc[dt][mt] = __builtin_amdgcn_mfma_f32_16x16x32_bf16(ahi[dt], blo[mt], acc[dt][mt], 0, 0, 0);
        acc[dt][mt] = __builtin_amdgcn_mfma_f32_16x16x32_bf16(alo[dt], bhi[mt], acc[dt][mt], 0, 0, 0);
      }
  }

  // ---- ksum: combine the 4 quads' s-subsets ----
#pragma unroll
  for (int dt = 0; dt < 2; ++dt) {
    ksacc[dt] += __shfl_xor(ksacc[dt], 16, 64);
    ksacc[dt] += __shfl_xor(ksacc[dt], 32, 64);
  }

  // ---- store partial: D layout col=lane&15, row=quad*4+reg ----
  float* po = part + (size_t)blockIdx.x * KV_ELEMS;
#pragma unroll
  for (int dt = 0; dt < 2; ++dt)
#pragma unroll
    for (int mt = 0; mt < 2; ++mt) {
      const int row = d_super + dt * 16 + q * 4;
      const int col = m_super + mt * 16 + p;
#pragma unroll
      for (int r = 0; r < 4; ++r)
        po[(row + r) * 64 + col] = acc[dt][mt][r];
    }
  if ((w & 1) == 0 && q < 2)                      // waves 0,2; lanes 0..31
    po[4096 + d_super + q * 16 + p] = ksacc[q];
}

// ---------------- Kernel B: reduce partials; emit kv m-major split hi/lo + ksum ----------------
__global__ __launch_bounds__(256) void kv_reduce_kernel(
    const float* __restrict__ part, short* __restrict__ kvh,
    short* __restrict__ kvl, float* __restrict__ ksum, int np)
{
  const int nh = blockIdx.x / 17;
  const int e  = (blockIdx.x % 17) * 256 + threadIdx.x;
  if (e >= KV_ELEMS) return;
  const float* pp = part + (size_t)nh * np * KV_ELEMS + e;
  float s = 0.f;
  for (int i = 0; i < np; ++i) s += pp[(size_t)i * KV_ELEMS];
  if (e < 4096) {
    const int d = e >> 6, m = e & 63;
    short hi, lo; split2(s, hi, lo);
    kvh[(size_t)nh * 4096 + m * 64 + d] = hi;     // m-major: C's B-frags read
    kvl[(size_t)nh * 4096 + m * 64 + d] = lo;     // contiguous d-runs
  } else {
    ksum[(size_t)nh * 64 + (e - 4096)] = s;
  }
}

// ---------------- Kernel C: out[l][m] = z_l * (phi(Q) . kvT) via MFMA ----------------
// wave w: m_super=(w&1)*32, row-half=(w>>1). kv B-frags resident in registers
// (8 frags = 32 VGPR); A frags built from global Q (d-contiguous); z on VALU.
__global__ __launch_bounds__(256) void attn_out_kernel(
    const float* __restrict__ Q, const short* __restrict__ kvh,
    const short* __restrict__ kvl, const float* __restrict__ ksumg,
    float* __restrict__ out)
{
  const int nh    = blockIdx.x / CCH;
  const int chunk = blockIdx.x % CCH;
  const int n = nh >> 3, h = nh & 7;
  const int tid = threadIdx.x;
  const int w = tid >> 6, lane = tid & 63;
  const int q = lane >> 4, p = lane & 15;
  const int m_super = (w & 1) * 32;
  const int rows_pb = LL / CCH;                       // 256
  const int row_base = chunk * rows_pb + (w >> 1) * (rows_pb / 2);

  const float* qbase = Q + ((size_t)n * LL * HH + h) * DD;

  // resident B frags: B[k=d = kst*32+q*8+j][n=m = m_super+mt*16+p]
  bf16x8 bh[2][2], bl[2][2];
#pragma unroll
  for (int mt = 0; mt < 2; ++mt)
#pragma unroll
    for (int kst = 0; kst < 2; ++kst) {
      const size_t off = (size_t)nh * 4096 + (m_super + mt * 16 + p) * 64 + kst * 32 + q * 8;
      bh[mt][kst] = *(const bf16x8*)(kvh + off);      // 16B aligned dwordx4
      bl[mt][kst] = *(const bf16x8*)(kvl + off);
    }
  // resident ksum: lane's d-runs
  float ksr[2][8];
#pragma unroll
  for (int kst = 0; kst < 2; ++kst) {
    const float* kp = ksumg + (size_t)nh * 64 + kst * 32 + q * 8;
    float4 a = *(const float4*)(kp), b = *(const float4*)(kp + 4);
    ksr[kst][0]=a.x; ksr[kst][1]=a.y; ksr[kst][2]=a.z; ksr[kst][3]=a.w;
    ksr[kst][4]=b.x; ksr[kst][5]=b.y; ksr[kst][6]=b.z; ksr[kst][7]=b.w;
  }

  for (int lt = 0; lt < rows_pb / 2 / 16; ++lt) {     // 8 ltiles of 16 rows
    const int l0 = row_base + lt * 16;
    f32x4 acc[2] = {};
    float zpart = 0.f;

#pragma unroll
    for (int kst = 0; kst < 2; ++kst) {
      // A frag: phi(Q)[l = l0+p][d = kst*32+q*8+j] — contiguous 8 floats
      const float* qp = qbase + (size_t)(l0 + p) * RS + kst * 32 + q * 8;
      float4 f0 = *(const float4*)(qp), f1 = *(const float4*)(qp + 4);
      float f[8] = {f0.x, f0.y, f0.z, f0.w, f1.x, f1.y, f1.z, f1.w};
      bf16x8 ah, al;
#pragma unroll
      for (int j = 0; j < 8; ++j) {
        f[j] = phi(f[j]);
        short hi, lo; split2(f[j], hi, lo);
        ah[j] = hi; al[j] = lo;
        zpart += f[j] * ksr[kst][j];
      }
#pragma unroll
      for (int mt = 0; mt < 2; ++mt) {
        acc[mt] = __builtin_amdgcn_mfma_f32_16x16x32_bf16(ah, bh[mt][kst], acc[mt], 0, 0, 0);
        acc[mt] = __builtin_amdgcn_mfma_f32_16x16x32_bf16(ah, bl[mt][kst], acc[mt], 0, 0, 0);
        acc[mt] = __builtin_amdgcn_mfma_f32_16x16x32_bf16(al, bh[mt][kst], acc[mt], 0, 0, 0);
      }
    }

    // z for row l0+(lane&15): combine quads' d-subsets
    zpart += __shfl_xor(zpart, 16, 64);
    zpart += __shfl_xor(zpart, 32, 64);
    const float z = 1.0f / (zpart + 1e-6f);
    // move z into D layout: D lane needs rows l0 + q*4 + r
    float zr[4];
#pragma unroll
    for (int r = 0; r < 4; ++r) zr[r] = __shfl(z, q * 4 + r, 64);

#pragma unroll
    for (int mt = 0; mt < 2; ++mt) {
      const int col = m_super + mt * 16 + p;
#pragma unroll
      for (int r = 0; r < 4; ++r) {
        const int row = l0 + q * 4 + r;
        out[((size_t)nh * LL + row) * DD + col] = acc[mt][r] * zr[r];
      }
    }
  }
}

extern "C" void kernel_launch(void* const* d_in, const int* in_sizes, int n_in,
                              void* d_out, int out_size, void* d_ws, size_t ws_size,
                              hipStream_t stream)
{
  const float* Q = (const float*)d_in[0];
  const float* K = (const float*)d_in[1];
  const float* V = (const float*)d_in[2];
  float* out = (float*)d_out;

  int sch = 32;
  while (sch > 1) {
    size_t need = (size_t)NH * sch * KV_ELEMS * 4     // partials
                + (size_t)NH * 4096 * 2 * 2           // kvh + kvl (bf16)
                + (size_t)NH * 64 * 4;                // ksum
    if (need <= ws_size) break;
    sch >>= 1;
  }
  float* part = (float*)d_ws;
  short* kvh  = (short*)((char*)d_ws + (size_t)NH * sch * KV_ELEMS * 4);
  short* kvl  = kvh + (size_t)NH * 4096;
  float* ksum = (float*)(kvl + (size_t)NH * 4096);

  hipLaunchKernelGGL(kv_partial_kernel, dim3(NH * sch), dim3(256), 0, stream,
                     K, V, part, sch);
  hipLaunchKernelGGL(kv_reduce_kernel, dim3(NH * 17), dim3(256), 0, stream,
                     part, kvh, kvl, ksum, sch);
  hipLaunchKernelGGL(attn_out_kernel, dim3(NH * CCH), dim3(256), 0, stream,
                     Q, kvh, kvl, ksum, out);
}